// Round 16
// baseline (80.471 us; speedup 1.0000x reference)
//
#include <hip/hip_runtime.h>

using u16 = unsigned short;
using u32 = unsigned int;
using u64 = unsigned long long;

// Fixed problem shape (guarded in the launcher; generic fallback otherwise).
constexpr int Bc = 2, Tc = 8, Fc = 5, Mc = 128, Sc = 128;
constexpr int Np = 65536;           // points per (b,t) slab
constexpr int CPTS = 256;           // points per chunk (4 per lane)
constexpr int NCHK = Np / CPTS;     // 256 chunks per slab
constexpr int NW = 10;              // waves per block (640 threads)
constexpr int CHUNK_BYTES = CPTS * Fc * 4;   // 5120 B per chunk

// Largest x with __fsqrt_rn(x) <= r (monotone correctly-rounded sqrt =>
// d2 <= sqrt_ub(r)  <=>  __fsqrt_rn(d2) <= r : the reference predicate, bit-exact).
__device__ __forceinline__ float sqrt_ub(float r) {
    float u = __fmul_rn(r, r);
    if (__fsqrt_rn(u) <= r) {
        while (true) {
            float nu = __uint_as_float(__float_as_uint(u) + 1u);
            if (__fsqrt_rn(nu) <= r) u = nu; else break;
        }
    } else {
        while (__fsqrt_rn(u) > r) u = __uint_as_float(__float_as_uint(u) - 1u);
    }
    return u;
}

__device__ __forceinline__ float box_radius(const float* __restrict__ box) {
    const float hl = __fmul_rn(0.5f, box[3]);
    const float hw = __fmul_rn(0.5f, box[4]);
    return __fmul_rn(__fsqrt_rn(__fadd_rn(__fmul_rn(hl, hl), __fmul_rn(hw, hw))), 1.1f);
}

// One block per (b,t,m) box; 10 waves; wave wv owns chunks c with c%10==wv.
// Counting stages a chunk into the wave's PRIVATE 5KB LDS slice via 5x
// global_load_lds (async DMA, zero VGPRs, issued back-to-back -> ONE memory
// round trip per chunk), then s_waitcnt vmcnt(0) + ds_read_b128 + ballots.
// Cross-wave TLP (5 waves/SIMD) hides the round trip. Geometric stages
// A/B/C = chunks 0..19 / 20..79 / 80..255; stage exits use a 256-wide shfl
// prefix + winners-only mask-emit (R13/R15-verified math).
__global__ __launch_bounds__(640) void k_box(
    const float* __restrict__ points,        // [B,T,N,F]
    const float* __restrict__ rois,          // [B,T,M,7]
    const int*   __restrict__ vlen,          // [B,T,M]
    float*       __restrict__ out)           // [B,M,T,S,F]
{
    const int blk = blockIdx.x;
    const int bt = blk & 15;                 // slab -> XCD pinning (blk%8 == bt%8)
    const int m  = blk >> 4;
    const int t = bt & 7, b = bt >> 3;

    int t_eff = t;
    if (t != 0 && vlen[bt * Mc + m] == 0) t_eff = 0;   // frame-0 fallback
    const int btE = b * Tc + t_eff;

    const float* box = rois + (size_t)(btE * Mc + m) * 7;
    const float cx = box[0], cy = box[1];
    const float T = sqrt_ub(box_radius(box));
    const float* pts = points + (size_t)btE * Np * Fc;
    float* orow = out + (size_t)((b * Mc + m) * Tc + t) * (Sc * Fc);

    __shared__ float s_stage[NW][CPTS * Fc]; // 50 KB: per-wave private chunk
    __shared__ u64 s_bal[NCHK][4];           // 8 KB ballot masks (k = 0..3)
    __shared__ u16 s_cnt[NCHK];              // per-chunk hit counts

    const int tid = threadIdx.x, lane = tid & 63, wv = tid >> 6;
    const u64 lt = (1ull << lane) - 1ull;

    // ---- count one 256-pt chunk: DMA-stage to LDS, one round trip ----------
    auto count_chunk = [&](int c) {
        const char* src = (const char*)(pts + (size_t)c * CPTS * Fc);
        char* dst = (char*)s_stage[wv];      // wave-uniform LDS base
        #pragma unroll
        for (int q = 0; q < 5; ++q) {
            __builtin_amdgcn_global_load_lds(
                (const __attribute__((address_space(1))) unsigned int*)(src + q * 1024 + lane * 16),
                (__attribute__((address_space(3))) unsigned int*)(dst + q * 1024),
                16, 0, 0);
        }
        asm volatile("s_waitcnt vmcnt(0)" ::: "memory");

        const float* P = &s_stage[wv][lane * 20];   // my 4 points (20 floats)
        const float4 v0 = *(const float4*)(P + 0);
        const float4 v1 = *(const float4*)(P + 4);
        const float4 v2 = *(const float4*)(P + 8);
        const float4 v3 = *(const float4*)(P + 12);
        const float4 v4 = *(const float4*)(P + 16);
        const float qx0 = v0.x, qy0 = v0.y;
        const float qx1 = v1.y, qy1 = v1.z;
        const float qx2 = v2.z, qy2 = v2.w;
        const float qx3 = v3.w, qy3 = v4.x;
        int cc = 0;
        #pragma unroll
        for (int k = 0; k < 4; ++k) {
            const float qx = k == 0 ? qx0 : k == 1 ? qx1 : k == 2 ? qx2 : qx3;
            const float qy = k == 0 ? qy0 : k == 1 ? qy1 : k == 2 ? qy2 : qy3;
            const float dx = __fsub_rn(qx, cx);
            const float dy = __fsub_rn(qy, cy);
            const float d2 = __fadd_rn(__fmul_rn(dx, dx), __fmul_rn(dy, dy));
            const u64 bb = __ballot(d2 <= T);
            if (lane == 0) s_bal[c][k] = bb;
            cc += (int)__popcll(bb);
        }
        if (lane == 0) s_cnt[c] = (u16)cc;
    };

    // ---- emit chunk c's winners from stored masks (verified math) ----------
    auto emit_chunk = [&](int c, int sb) {
        const u64 b0 = s_bal[c][0], b1 = s_bal[c][1];
        const u64 b2 = s_bal[c][2], b3 = s_bal[c][3];
        const int below = (int)(__popcll(b0 & lt) + __popcll(b1 & lt) +
                                __popcll(b2 & lt) + __popcll(b3 & lt));
        const int pidx0 = c * CPTS + lane * 4;
        int ownpre = 0;
        #pragma unroll
        for (int k = 0; k < 4; ++k) {
            const u64 bk = k == 0 ? b0 : k == 1 ? b1 : k == 2 ? b2 : b3;
            if ((bk >> lane) & 1ull) {
                const int slot = sb + below + ownpre;
                if (slot < Sc) {
                    const float* p = pts + (size_t)(pidx0 + k) * Fc;
                    float* o = orow + (size_t)slot * Fc;
                    o[0] = p[0]; o[1] = p[1]; o[2] = p[2]; o[3] = p[3]; o[4] = p[4];
                }
                ++ownpre;
            }
        }
    };

    // ---- 256-wide prefix over s_cnt (4 u16 per lane) -----------------------
    int p_excl, p_a0, p_a1, p_a2, p_total;
    auto prefix256 = [&]() {
        const u64 four = ((const u64*)s_cnt)[lane];
        p_a0 = (int)(four & 0xFFFFu);
        p_a1 = (int)((four >> 16) & 0xFFFFu);
        p_a2 = (int)((four >> 32) & 0xFFFFu);
        const int a3 = (int)(four >> 48);
        const int ssum = p_a0 + p_a1 + p_a2 + a3;
        int incl = ssum;
        #pragma unroll
        for (int d = 1; d < 64; d <<= 1) { int v = __shfl_up(incl, d); if (lane >= d) incl += v; }
        p_excl  = incl - ssum;               // base of chunk 4*lane
        p_total = __shfl(incl, 63);
    };

    // ---- winners-only emit over owned chunks (c % 10 == wv) ----------------
    auto emit_all = [&]() {
        for (int j = 0; NW * j + wv < NCHK; ++j) {
            const int c = NW * j + wv;
            if ((int)s_cnt[c] == 0) continue;
            const int sl = c >> 2, ci = c & 3;
            int base = __shfl(p_excl, sl);
            if (ci > 0) base += __shfl(p_a0, sl);
            if (ci > 1) base += __shfl(p_a1, sl);
            if (ci > 2) base += __shfl(p_a2, sl);
            if (base >= Sc) break;           // bases monotone per wave
            emit_chunk(c, base);
        }
    };

    // zero chunks not counted by stage A (A covers 0..19)
    if (tid >= 2 * NW && tid < NCHK) s_cnt[tid] = 0;

    // ================= Stage A: chunks 0..19 (5120 points) ==================
    count_chunk(wv);
    count_chunk(NW + wv);
    __syncthreads();
    prefix256();
    __syncthreads();                          // prefix reads done before B writes
    if (p_total >= Sc) { emit_all(); return; }

    // ================= Stage B: chunks 20..79 (+15360 points) ===============
    #pragma unroll
    for (int j = 2; j < 8; ++j) count_chunk(NW * j + wv);
    __syncthreads();
    prefix256();
    __syncthreads();                          // prefix reads done before C writes
    if (p_total >= Sc) { emit_all(); return; }

    // ================= Stage C: chunks 80..255 (+45056 points) ==============
    for (int j = 8; NW * j + wv < NCHK; ++j) count_chunk(NW * j + wv);
    __syncthreads();
    prefix256();
    emit_all();

    // tail zero [min(total,S), S)
    const int fill = p_total < Sc ? p_total : Sc;
    for (int i = fill * Fc + tid; i < Sc * Fc; i += 640) orow[i] = 0.0f;
}

// ---------------- fallback: R2 single-kernel path (shape-generic) ------------
__global__ __launch_bounds__(1024) void vox_pool(
    const float* __restrict__ points, const float* __restrict__ rois,
    const int* __restrict__ valid_length, float* __restrict__ out,
    int N, int M, int S)
{
    const int blk = blockIdx.x;
    const int m = blk % M;
    const int t = (blk / M) % Tc;
    const int b = blk / (M * Tc);
    int t_eff = t;
    if (t != 0 && valid_length[(b * Tc + t) * M + m] == 0) t_eff = 0;
    const float* box = rois + (size_t)((b * Tc + t_eff) * M + m) * 7;
    const float cx = box[0], cy = box[1];
    const float r = box_radius(box);
    const float* pts = points + (size_t)(b * Tc + t_eff) * N * Fc;
    float* o = out + ((size_t)(b * M + m) * Tc + t) * (size_t)S * Fc;
    __shared__ int wcnt[16];
    const int tid = threadIdx.x, lane = tid & 63, wav = tid >> 6;
    const int nthreads = blockDim.x, nwaves = nthreads >> 6;
    int cnt = 0;
    for (int basei = 0; basei < N; basei += nthreads) {
        const int idx = basei + tid;
        bool inside = false;
        if (idx < N) {
            const float dx = __fsub_rn(pts[(size_t)idx * Fc + 0], cx);
            const float dy = __fsub_rn(pts[(size_t)idx * Fc + 1], cy);
            const float d2 = __fadd_rn(__fmul_rn(dx, dx), __fmul_rn(dy, dy));
            inside = (__fsqrt_rn(d2) <= r);
        }
        const unsigned long long bal = __ballot(inside);
        if (lane == 0) wcnt[wav] = __popcll(bal);
        __syncthreads();
        int wave_off = 0, block_tot = 0;
        for (int w = 0; w < nwaves; ++w) {
            const int c = wcnt[w];
            if (w < wav) wave_off += c;
            block_tot += c;
        }
        if (inside) {
            const int slot = cnt + wave_off + (int)__popcll(bal & ((1ull << lane) - 1ull));
            if (slot < S)
                for (int f = 0; f < Fc; ++f)
                    o[(size_t)slot * Fc + f] = pts[(size_t)idx * Fc + f];
        }
        cnt += block_tot;
        __syncthreads();
        if (cnt >= S) break;
    }
    const int filled = cnt < S ? cnt : S;
    for (int s = filled + tid; s < S; s += nthreads)
        for (int f = 0; f < Fc; ++f)
            o[(size_t)s * Fc + f] = 0.0f;
}

extern "C" void kernel_launch(void* const* d_in, const int* in_sizes, int n_in,
                              void* d_out, int out_size, void* d_ws, size_t ws_size,
                              hipStream_t stream) {
    const float* points = (const float*)d_in[0];
    const float* rois   = (const float*)d_in[1];
    const int*   vlen   = (const int*)d_in[2];
    float* out = (float*)d_out;

    const bool fixed =
        in_sizes[0] == Bc * Tc * Np * Fc &&
        in_sizes[1] == Bc * Tc * Mc * 7 &&
        in_sizes[2] == Bc * Tc * Mc &&
        out_size    == Bc * Mc * Tc * Sc * Fc;

    if (fixed) {
        k_box<<<dim3(Bc * Tc * Mc), 640, 0, stream>>>(points, rois, vlen, out);
    } else {
        const int N = in_sizes[0] / (Bc * Tc * Fc);
        const int M = in_sizes[2] / (Bc * Tc);
        const int S = out_size / (Bc * M * Tc * Fc);
        vox_pool<<<dim3(Bc * Tc * M), 1024, 0, stream>>>(points, rois, vlen, out, N, M, S);
    }
}

// Round 17
// 70.738 us; speedup vs baseline: 1.1376x; 1.1376x over previous
//
#include <hip/hip_runtime.h>

using u16 = unsigned short;
using u32 = unsigned int;
using u64 = unsigned long long;

// Fixed problem shape (guarded in the launcher; generic fallback otherwise).
constexpr int Bc = 2, Tc = 8, Fc = 5, Mc = 128, Sc = 128;
constexpr int Np = 65536;           // points per (b,t) slab
constexpr int CPTS = 256;           // points per chunk (4 per lane)
constexpr int NCHK = Np / CPTS;     // 256 chunks per slab
constexpr int NBT = Bc * Tc;        // 16 slabs

// Largest x with __fsqrt_rn(x) <= r (monotone correctly-rounded sqrt =>
// d2 <= sqrt_ub(r)  <=>  __fsqrt_rn(d2) <= r : the reference predicate, bit-exact).
__device__ __forceinline__ float sqrt_ub(float r) {
    float u = __fmul_rn(r, r);
    if (__fsqrt_rn(u) <= r) {
        while (true) {
            float nu = __uint_as_float(__float_as_uint(u) + 1u);
            if (__fsqrt_rn(nu) <= r) u = nu; else break;
        }
    } else {
        while (__fsqrt_rn(u) > r) u = __uint_as_float(__float_as_uint(u) - 1u);
    }
    return u;
}

__device__ __forceinline__ float box_radius(const float* __restrict__ box) {
    const float hl = __fmul_rn(0.5f, box[3]);
    const float hw = __fmul_rn(0.5f, box[4]);
    return __fmul_rn(__fsqrt_rn(__fadd_rn(__fmul_rn(hl, hl), __fmul_rn(hw, hw))), 1.1f);
}

// ---------------- K1: count ALL (active box, chunk) pairs --------------------
// 1024 blocks x 256 thr; bt = blk&15, wave wv owns chunk (blk>>4)*4+wv.
// One 5xfloat4 batch per lane, then a dense 128-box ballot loop (VALU-bound,
// fixed work, no early exits => throughput regime, TLP hides the one load).
__global__ __launch_bounds__(256) void k_count(
    const float* __restrict__ points, const float* __restrict__ rois,
    const int* __restrict__ vlen, u16* __restrict__ cnt)
{
    __shared__ float sX[Mc], sY[Mc], sT[Mc];
    __shared__ int sAct[Mc];
    const int bt  = blockIdx.x & (NBT - 1);
    const int grp = blockIdx.x >> 4;
    const int t   = bt & 7;
    const int tid = threadIdx.x;
    if (tid < Mc) {
        const int act = (t == 0) || (vlen[bt * Mc + tid] != 0);
        sAct[tid] = act;
        if (act) {
            const float* box = rois + (size_t)(bt * Mc + tid) * 7;
            sX[tid] = box[0]; sY[tid] = box[1]; sT[tid] = sqrt_ub(box_radius(box));
        }
    }
    __syncthreads();

    const int lane = tid & 63, wv = tid >> 6;
    const int chunk = grp * 4 + wv;
    const float* pc = points + ((size_t)bt * Np + (size_t)chunk * CPTS) * Fc;

    // one 5xfloat4 batch: 4 consecutive points per lane
    const float4* src = (const float4*)(pc + (size_t)(lane * 4) * Fc);
    const float4 v0 = src[0], v1 = src[1], v2 = src[2], v3 = src[3], v4 = src[4];
    const float qx0 = v0.x, qy0 = v0.y;
    const float qx1 = v1.y, qy1 = v1.z;
    const float qx2 = v2.z, qy2 = v2.w;
    const float qx3 = v3.w, qy3 = v4.x;

    for (int m = 0; m < Mc; ++m) {
        if (!sAct[m]) continue;                 // wave-uniform skip
        const float cx = sX[m], cy = sY[m], T = sT[m];
        int cc = 0;
        #pragma unroll
        for (int k = 0; k < 4; ++k) {
            const float qx = k == 0 ? qx0 : k == 1 ? qx1 : k == 2 ? qx2 : qx3;
            const float qy = k == 0 ? qy0 : k == 1 ? qy1 : k == 2 ? qy2 : qy3;
            const float dx = __fsub_rn(qx, cx);
            const float dy = __fsub_rn(qy, cy);
            const float d2 = __fadd_rn(__fmul_rn(dx, dx), __fmul_rn(dy, dy));
            cc += (int)__popcll(__ballot(d2 <= T));
        }
        if (lane == 0) cnt[((size_t)(bt * Mc + m)) * NCHK + chunk] = (u16)cc;
    }
}

// ---------------- K2: per-box emit, zero barriers ----------------------------
// 2048 blocks x 256 thr (4 waves). Every wave redundantly loads the box's
// 256-count row (u64/lane), does the verified shfl prefix, then walks its
// chunks c (c%4 == wv): skip cnt==0, break base>=S (monotone), recount the
// deterministic ballots and emit winners at exact slots. Tail-zero from total.
__global__ __launch_bounds__(256) void k_emit(
    const float* __restrict__ points, const float* __restrict__ rois,
    const int* __restrict__ vlen, const u16* __restrict__ cnt,
    float* __restrict__ out)
{
    const int row = blockIdx.x;                // bt*Mc + m
    const int bt = row >> 7, m = row & (Mc - 1);
    const int t = bt & 7, b = bt >> 3;

    int t_eff = t;
    if (t != 0 && vlen[row] == 0) t_eff = 0;   // frame-0 fallback
    const int btE = b * Tc + t_eff;

    const float* box = rois + (size_t)(btE * Mc + m) * 7;
    const float cx = box[0], cy = box[1];
    const float T = sqrt_ub(box_radius(box));
    const float* pts = points + (size_t)btE * Np * Fc;
    float* orow = out + (size_t)((b * Mc + m) * Tc + t) * (Sc * Fc);

    const int tid = threadIdx.x, lane = tid & 63, wv = tid >> 6;
    const u64 lt = (1ull << lane) - 1ull;

    // counts row of the EFFECTIVE box (frame-0 rows are always counted)
    const u16* crow = cnt + (size_t)(btE * Mc + m) * NCHK;
    const u64 four = ((const u64*)crow)[lane]; // counts of chunks 4l..4l+3
    const int a0 = (int)(four & 0xFFFFu);
    const int a1 = (int)((four >> 16) & 0xFFFFu);
    const int a2 = (int)((four >> 32) & 0xFFFFu);
    const int a3 = (int)(four >> 48);
    const int ssum = a0 + a1 + a2 + a3;
    int incl = ssum;
    #pragma unroll
    for (int d = 1; d < 64; d <<= 1) { int v = __shfl_up(incl, d); if (lane >= d) incl += v; }
    const int excl  = incl - ssum;             // base of chunk 4*lane
    const int total = __shfl(incl, 63);

    // my per-lane count for wave's parity: chunk 4*lane + wv
    const int amy = wv == 0 ? a0 : wv == 1 ? a1 : wv == 2 ? a2 : a3;
    // base of chunk 4*lane + wv
    int bmy = excl;
    if (wv > 0) bmy += a0;
    if (wv > 1) bmy += a1;
    if (wv > 2) bmy += a2;

    // walk my chunks c = 4j + wv (count/base via shfl from lane j)
    for (int j = 0; j < 64; ++j) {
        const int ccj = __shfl(amy, j);
        const int bcj = __shfl(bmy, j);
        if (ccj == 0) continue;
        if (bcj >= Sc) break;                  // bases monotone in j
        const int c = 4 * j + wv;

        const float4* src = (const float4*)(pts + ((size_t)c * CPTS + lane * 4) * Fc);
        const float4 v0 = src[0], v1 = src[1], v2 = src[2], v3 = src[3], v4 = src[4];
        const float qx0 = v0.x, qy0 = v0.y;
        const float qx1 = v1.y, qy1 = v1.z;
        const float qx2 = v2.z, qy2 = v2.w;
        const float qx3 = v3.w, qy3 = v4.x;

        u64 bal[4];
        #pragma unroll
        for (int k = 0; k < 4; ++k) {
            const float qx = k == 0 ? qx0 : k == 1 ? qx1 : k == 2 ? qx2 : qx3;
            const float qy = k == 0 ? qy0 : k == 1 ? qy1 : k == 2 ? qy2 : qy3;
            const float dx = __fsub_rn(qx, cx);
            const float dy = __fsub_rn(qy, cy);
            const float d2 = __fadd_rn(__fmul_rn(dx, dx), __fmul_rn(dy, dy));
            bal[k] = __ballot(d2 <= T);
        }
        const int below = (int)(__popcll(bal[0] & lt) + __popcll(bal[1] & lt) +
                                __popcll(bal[2] & lt) + __popcll(bal[3] & lt));
        int ownpre = 0;
        #pragma unroll
        for (int k = 0; k < 4; ++k) {
            if ((bal[k] >> lane) & 1ull) {
                const int slot = bcj + below + ownpre;
                if (slot < Sc) {
                    const float qx = k == 0 ? qx0 : k == 1 ? qx1 : k == 2 ? qx2 : qx3;
                    const float qy = k == 0 ? qy0 : k == 1 ? qy1 : k == 2 ? qy2 : qy3;
                    const float* p = pts + (size_t)(c * CPTS + lane * 4 + k) * Fc;
                    float* o = orow + (size_t)slot * Fc;
                    o[0] = qx; o[1] = qy; o[2] = p[2]; o[3] = p[3]; o[4] = p[4];
                }
                ++ownpre;
            }
        }
    }

    // tail zero [min(total,S), S)
    const int fill = total < Sc ? total : Sc;
    for (int i = fill * Fc + tid; i < Sc * Fc; i += 256) orow[i] = 0.0f;
}

// ---------------- fallback: R2 single-kernel path (shape-generic) ------------
__global__ __launch_bounds__(1024) void vox_pool(
    const float* __restrict__ points, const float* __restrict__ rois,
    const int* __restrict__ valid_length, float* __restrict__ out,
    int N, int M, int S)
{
    const int blk = blockIdx.x;
    const int m = blk % M;
    const int t = (blk / M) % Tc;
    const int b = blk / (M * Tc);
    int t_eff = t;
    if (t != 0 && valid_length[(b * Tc + t) * M + m] == 0) t_eff = 0;
    const float* box = rois + (size_t)((b * Tc + t_eff) * M + m) * 7;
    const float cx = box[0], cy = box[1];
    const float r = box_radius(box);
    const float* pts = points + (size_t)(b * Tc + t_eff) * N * Fc;
    float* o = out + ((size_t)(b * M + m) * Tc + t) * (size_t)S * Fc;
    __shared__ int wcnt[16];
    const int tid = threadIdx.x, lane = tid & 63, wav = tid >> 6;
    const int nthreads = blockDim.x, nwaves = nthreads >> 6;
    int cnt = 0;
    for (int basei = 0; basei < N; basei += nthreads) {
        const int idx = basei + tid;
        bool inside = false;
        if (idx < N) {
            const float dx = __fsub_rn(pts[(size_t)idx * Fc + 0], cx);
            const float dy = __fsub_rn(pts[(size_t)idx * Fc + 1], cy);
            const float d2 = __fadd_rn(__fmul_rn(dx, dx), __fmul_rn(dy, dy));
            inside = (__fsqrt_rn(d2) <= r);
        }
        const unsigned long long bal = __ballot(inside);
        if (lane == 0) wcnt[wav] = __popcll(bal);
        __syncthreads();
        int wave_off = 0, block_tot = 0;
        for (int w = 0; w < nwaves; ++w) {
            const int c = wcnt[w];
            if (w < wav) wave_off += c;
            block_tot += c;
        }
        if (inside) {
            const int slot = cnt + wave_off + (int)__popcll(bal & ((1ull << lane) - 1ull));
            if (slot < S)
                for (int f = 0; f < Fc; ++f)
                    o[(size_t)slot * Fc + f] = pts[(size_t)idx * Fc + f];
        }
        cnt += block_tot;
        __syncthreads();
        if (cnt >= S) break;
    }
    const int filled = cnt < S ? cnt : S;
    for (int s = filled + tid; s < S; s += nthreads)
        for (int f = 0; f < Fc; ++f)
            o[(size_t)s * Fc + f] = 0.0f;
}

extern "C" void kernel_launch(void* const* d_in, const int* in_sizes, int n_in,
                              void* d_out, int out_size, void* d_ws, size_t ws_size,
                              hipStream_t stream) {
    const float* points = (const float*)d_in[0];
    const float* rois   = (const float*)d_in[1];
    const int*   vlen   = (const int*)d_in[2];
    float* out = (float*)d_out;

    const size_t cnt_bytes = (size_t)NBT * Mc * NCHK * sizeof(u16);  // 1 MiB

    const bool fixed =
        in_sizes[0] == Bc * Tc * Np * Fc &&
        in_sizes[1] == Bc * Tc * Mc * 7 &&
        in_sizes[2] == Bc * Tc * Mc &&
        out_size    == Bc * Mc * Tc * Sc * Fc &&
        ws_size     >= cnt_bytes;

    if (fixed) {
        u16* cnt = (u16*)d_ws;
        k_count<<<dim3(NBT * (NCHK / 4)), 256, 0, stream>>>(points, rois, vlen, cnt);
        k_emit <<<dim3(NBT * Mc),         256, 0, stream>>>(points, rois, vlen, cnt, out);
    } else {
        const int N = in_sizes[0] / (Bc * Tc * Fc);
        const int M = in_sizes[2] / (Bc * Tc);
        const int S = out_size / (Bc * M * Tc * Fc);
        vox_pool<<<dim3(Bc * Tc * M), 1024, 0, stream>>>(points, rois, vlen, out, N, M, S);
    }
}